// Round 17
// baseline (537.510 us; speedup 1.0000x reference)
//
#include <hip/hip_runtime.h>
#include <stdint.h>

// Problem: B=4096, S=256, F=64, K=16, L=256
//   logits[b,k,f] = sum_s x[b,s,f] * W[f,s,k]   (x NaN->0)
//   idx[b,f] = argmax_k logits[b,k,f]           (first max wins)
//   out[b,f,l] = snippet_list[f, idx[b,f], l]
constexpr int Bn = 4096, Sn = 256, Fn = 64, Kn = 16;

// W[f][s][k] -> Wl[s][kq][f][r]  (float4 view: Wl4[(s*4+kq)*64+f])
__global__ void transpose_w_kernel(const float* __restrict__ W, float* __restrict__ Wl) {
  int t = blockIdx.x * 256 + threadIdx.x;          // t = ((s*4+kq)*64+f)*4+r
  int r = t & 3, f = (t >> 2) & 63, kq = (t >> 8) & 3, s = t >> 10;
  Wl[t] = W[(f * Sn + s) * Kn + kq * 4 + r];
}

// async global->LDS, 16B per lane; LDS dest = wave-uniform base + lane*16
__device__ __forceinline__ void gld_lds16(const float4* g, float4* l) {
  __builtin_amdgcn_global_load_lds(
      (const __attribute__((address_space(1))) uint32_t*)g,
      (__attribute__((address_space(3))) uint32_t*)l, 16, 0, 0);
}

// counted-vmcnt barrier: waits only for this phase's W stage (8 gld_lds,
// with exactly 16 x-loads issued after it), NOT the deep x prefetch.
#define SYNC16()                                              \
  {                                                           \
    asm volatile("s_waitcnt vmcnt(16)" ::: "memory");         \
    __builtin_amdgcn_sched_barrier(0);                        \
    __builtin_amdgcn_s_barrier();                             \
    __builtin_amdgcn_sched_barrier(0);                        \
  }

// FUSED gemm+argmax+gather. R16 geometry (bt=4, 2 s-halves, 4-s chunks,
// 64 KB W dbuf) + deep pipeline: x register-prefetched 3 phases ahead
// (4 rotating 16-reg buffers), counted-vmcnt barrier instead of the
// vmcnt(0)-draining __syncthreads. Queue bookkeeping kept constant via
// wrap-around dummy STAGEW/LOADX ((c+k)&31, never consumed).
// Grid 512 x 256 (4 waves): q=w&1 batch-quad, h=w>>1 s-half;
// batches blk*8+q*4+{0..3}, s in [h*128,h*128+128), lane = f.
__global__ __launch_bounds__(256, 2) void fused_kernel(
    const float* __restrict__ x, const float4* __restrict__ Wl4,
    const float4* __restrict__ snip4, float4* __restrict__ out4) {
  __shared__ float4 Wbuf[2][2][1024];  // [half][parity][(s4*4+kq)*64+f] 64 KB
  __shared__ int idxs[8][64];          // [q*4+j][f]                     2 KB

  const int tid = threadIdx.x;
  const int lane = tid & 63;            // f
  const int w = tid >> 6;               // 0..3
  const int q = w & 1;                  // batch quad
  const int h = w >> 1;                 // s-half
  const int bbase = blockIdx.x * 8;
  const int b0 = bbase + q * 4;
  const size_t xrow = (size_t)Sn * Fn;
  const float* xb0 = x + (size_t)b0 * xrow + (size_t)(h * 128) * Fn + lane;
  const float4* wsrc0 = Wl4 + (size_t)(h * 128) * 256;  // this half's W rows

  float acc[4][16];
#pragma unroll
  for (int j = 0; j < 4; ++j)
#pragma unroll
    for (int k = 0; k < 16; ++k) acc[j][k] = 0.f;

  float x0[4][4], x1[4][4], x2[4][4], x3[4][4];  // 4 rotating x buffers

// stage W chunk c (4 s-rows = 16 KB) into Wbuf[h][p]; wave (q,h) stages
// rows {c*4+2q, c*4+2q+1} = 8 x 1KB gld_lds  (8 vmem ops)
#define STAGEW(c, p)                                                         \
  {                                                                          \
    const float4* _src = wsrc0 + (size_t)((c) * 4 + 2 * q) * 256 + lane;     \
    float4* _dst = &Wbuf[h][p][(2 * q) * 256];                               \
    _Pragma("unroll") for (int ii = 0; ii < 8; ++ii)                         \
        gld_lds16(_src + ii * 64, _dst + ii * 64);                           \
  }

// load x chunk c (4 s x 4 b, 256 B coalesced; 16 vmem ops)
#define LOADX(c, xn)                                                         \
  {                                                                          \
    _Pragma("unroll") for (int s4 = 0; s4 < 4; ++s4)                         \
        _Pragma("unroll") for (int j = 0; j < 4; ++j)                        \
            xn[s4][j] = xb0[(size_t)j * xrow + (size_t)((c) * 4 + s4) * Fn]; \
  }

// compute chunk from Wbuf[h][p] and x buffer xn (NaN->0 applied at use)
#define COMPUTE(p, xn)                                                       \
  {                                                                          \
    _Pragma("unroll") for (int s4 = 0; s4 < 4; ++s4) {                       \
      float4 wq[4];                                                          \
      _Pragma("unroll") for (int kq = 0; kq < 4; ++kq)                       \
          wq[kq] = Wbuf[h][p][(s4 * 4 + kq) * 64 + lane];                    \
      float xv[4];                                                           \
      _Pragma("unroll") for (int j = 0; j < 4; ++j) {                        \
        float v = xn[s4][j];                                                 \
        xv[j] = (v == v) ? v : 0.f;                                          \
      }                                                                      \
      _Pragma("unroll") for (int j = 0; j < 4; ++j)                          \
          _Pragma("unroll") for (int kq = 0; kq < 4; ++kq) {                 \
        acc[j][4 * kq + 0] = fmaf(xv[j], wq[kq].x, acc[j][4 * kq + 0]);      \
        acc[j][4 * kq + 1] = fmaf(xv[j], wq[kq].y, acc[j][4 * kq + 1]);      \
        acc[j][4 * kq + 2] = fmaf(xv[j], wq[kq].z, acc[j][4 * kq + 2]);      \
        acc[j][4 * kq + 3] = fmaf(xv[j], wq[kq].w, acc[j][4 * kq + 3]);      \
      }                                                                      \
    }                                                                        \
  }

// one pipeline phase for chunk c: barrier (W(c) ready), issue W(c+1) and
// x(c+3) (wrap-masked -> constant vmcnt bookkeeping), compute chunk c.
#define PHASE(c, xcur, xnext, p)                                             \
  {                                                                          \
    SYNC16();                                                                \
    STAGEW(((c) + 1) & 31, (p) ^ 1);                                         \
    LOADX(((c) + 3) & 31, xnext);                                            \
    COMPUTE(p, xcur);                                                        \
  }

  // prologue: x(0), x(1), W(0), x(2)  ->  16 ops after W(0) => SYNC16 ok
  LOADX(0, x0);
  LOADX(1, x1);
  STAGEW(0, 0);
  LOADX(2, x2);

  // 32 chunks, 4-unrolled for static buffer rotation; parity = c&1
  for (int cc = 0; cc < 32; cc += 4) {
    PHASE(cc + 0, x0, x3, 0);
    PHASE(cc + 1, x1, x0, 1);
    PHASE(cc + 2, x2, x1, 0);
    PHASE(cc + 3, x3, x2, 1);
  }

  // full drain before aliasing Wbuf (dummy stages still in flight)
  __syncthreads();

  // cross-half reduce in aliased Wbuf, then argmax
  float* red = reinterpret_cast<float*>(&Wbuf[0][0][0]);
  if (h == 1) {
#pragma unroll
    for (int j = 0; j < 4; ++j)
#pragma unroll
      for (int k = 0; k < 16; ++k)
        red[((q * 4 + j) * 16 + k) * 64 + lane] = acc[j][k];
  }
  __syncthreads();
  if (h == 0) {
#pragma unroll
    for (int j = 0; j < 4; ++j) {
#pragma unroll
      for (int k = 0; k < 16; ++k)
        acc[j][k] += red[((q * 4 + j) * 16 + k) * 64 + lane];
      float bv = acc[j][0];
      int bk = 0;
#pragma unroll
      for (int k = 1; k < 16; ++k)
        if (acc[j][k] > bv) { bv = acc[j][k]; bk = k; }  // first max wins
      idxs[q * 4 + j][lane] = bk;
    }
  }
  __syncthreads();

  // fused gather: 8 b * 64 f = 512 rows of 1 KB, coalesced float4
#pragma unroll 4
  for (int it = 0; it < 128; ++it) {
    int r = (it << 2) | w;
    int bi = r >> 6, f = r & 63;
    int kk = idxs[bi][f];
    float4 v = snip4[(size_t)((f * Kn + kk) << 6) + lane];
    out4[((size_t)(bbase + bi) * Fn + f) * 64 + lane] = v;
  }
#undef STAGEW
#undef LOADX
#undef COMPUTE
#undef PHASE
}

// Fallback (ws too small): R5's verified fused kernel, direct W reads.
__global__ __launch_bounds__(256, 2) void fused_fallback(
    const float* __restrict__ x, const float* __restrict__ Wsrc,
    const float4* __restrict__ snip4, float4* __restrict__ out4) {
  __shared__ int idxs[8][64];
  const int tid = threadIdx.x;
  const int lane = tid & 63;
  const int w = tid >> 6;
  const int bbase = blockIdx.x * 8;
  const int b0 = bbase + w * 2;
  const size_t xrow = (size_t)Sn * Fn;

  float acc0[16], acc1[16];
#pragma unroll
  for (int k = 0; k < 16; ++k) { acc0[k] = 0.f; acc1[k] = 0.f; }
  const float* pc0 = x + (size_t)b0 * xrow + lane;
  const float* pc1 = pc0 + xrow;
  float xc0[8], xc1[8], xn0[8], xn1[8];
#pragma unroll
  for (int j = 0; j < 8; ++j) { xn0[j] = pc0[j * 64]; xn1[j] = pc1[j * 64]; }
  for (int c = 0; c < 32; ++c) {
#pragma unroll
    for (int j = 0; j < 8; ++j) {
      float v0 = xn0[j], v1 = xn1[j];
      xc0[j] = (v0 == v0) ? v0 : 0.f;
      xc1[j] = (v1 == v1) ? v1 : 0.f;
    }
    if (c < 31) {
      pc0 += 512; pc1 += 512;
#pragma unroll
      for (int j = 0; j < 8; ++j) { xn0[j] = pc0[j * 64]; xn1[j] = pc1[j * 64]; }
    }
#pragma unroll
    for (int s8 = 0; s8 < 8; ++s8) {
      const int s = c * 8 + s8;
      float wv[16];
      const float4* wq = reinterpret_cast<const float4*>(Wsrc) + ((size_t)(lane * Sn + s) << 2);
#pragma unroll
      for (int jj = 0; jj < 4; ++jj) {
        float4 qv = wq[jj];
        wv[4 * jj + 0] = qv.x; wv[4 * jj + 1] = qv.y; wv[4 * jj + 2] = qv.z; wv[4 * jj + 3] = qv.w;
      }
#pragma unroll
      for (int k = 0; k < 16; ++k) {
        acc0[k] = fmaf(xc0[s8], wv[k], acc0[k]);
        acc1[k] = fmaf(xc1[s8], wv[k], acc1[k]);
      }
    }
  }
  {
    float bv0 = acc0[0], bv1 = acc1[0];
    int bk0 = 0, bk1 = 0;
#pragma unroll
    for (int k = 1; k < 16; ++k) {
      if (acc0[k] > bv0) { bv0 = acc0[k]; bk0 = k; }
      if (acc1[k] > bv1) { bv1 = acc1[k]; bk1 = k; }
    }
    idxs[w * 2 + 0][lane] = bk0;
    idxs[w * 2 + 1][lane] = bk1;
  }
  __syncthreads();
#pragma unroll 4
  for (int it = 0; it < 128; ++it) {
    int r = (it << 2) | w;
    int bi = r >> 6, f = r & 63;
    int kk = idxs[bi][f];
    float4 v = snip4[(size_t)((f * Kn + kk) << 6) + lane];
    out4[((size_t)(bbase + bi) * Fn + f) * 64 + lane] = v;
  }
}

extern "C" void kernel_launch(void* const* d_in, const int* in_sizes, int n_in,
                              void* d_out, int out_size, void* d_ws, size_t ws_size,
                              hipStream_t stream) {
  const float* x = (const float*)d_in[0];
  const float* W = (const float*)d_in[1];
  const float* snip = (const float*)d_in[2];
  float4* out4 = (float4*)d_out;
  const float4* snip4 = (const float4*)snip;

  const size_t wl_bytes = (size_t)Sn * Fn * Kn * sizeof(float);   // 1 MB
  if (ws_size >= wl_bytes) {
    float* Wl = (float*)d_ws;
    transpose_w_kernel<<<(Sn * Fn * Kn) / 256, 256, 0, stream>>>(W, Wl);
    fused_kernel<<<Bn / 8, 256, 0, stream>>>(x, (const float4*)Wl, snip4, out4);
  } else {
    fused_fallback<<<Bn / 8, 256, 0, stream>>>(x, W, snip4, out4);
  }
}

// Round 19
// 193.942 us; speedup vs baseline: 2.7715x; 2.7715x over previous
//
#include <hip/hip_runtime.h>
#include <stdint.h>

// Problem: B=4096, S=256, F=64, K=16, L=256
//   logits[b,k,f] = sum_s x[b,s,f] * W[f,s,k]   (x NaN->0)
//   idx[b,f] = argmax_k logits[b,k,f]           (first max wins)
//   out[b,f,l] = snippet_list[f, idx[b,f], l]
constexpr int Bn = 4096, Sn = 256, Fn = 64, Kn = 16;

// W[f][s][k] -> Wl[s][kq][f][r]  (float4 view: Wl4[(s*4+kq)*64+f])
__global__ void transpose_w_kernel(const float* __restrict__ W, float* __restrict__ Wl) {
  int t = blockIdx.x * 256 + threadIdx.x;          // t = ((s*4+kq)*64+f)*4+r
  int r = t & 3, f = (t >> 2) & 63, kq = (t >> 8) & 3, s = t >> 10;
  Wl[t] = W[(f * Sn + s) * Kn + kq * 4 + r];
}

// raw barrier that does NOT drain vmcnt: LDS ops settled, x prefetch and
// W reg-loads stay in flight. All vmcnt waits are compiler-derived.
#define BARRIER()                                             \
  {                                                           \
    asm volatile("s_waitcnt lgkmcnt(0)" ::: "memory");        \
    __builtin_amdgcn_sched_barrier(0);                        \
    __builtin_amdgcn_s_barrier();                             \
    __builtin_amdgcn_sched_barrier(0);                        \
  }

// FUSED gemm+argmax+gather. R16 geometry (bt=4, 2 s-halves, 4-s W chunks,
// 64 KB W dbuf) + deep pipeline with COMPILER-MANAGED waits:
//  - W reg-staged (T14): global->wst[8] issued at TOP of phase c (before
//    x loads, so in-order vmcnt never makes W wait on x), ds_write at END
//    of the phase; compiler emits the exact counted vmcnt for wst.
//  - x prefetched 3 phases ahead in 4 rotating static buffers.
//  - raw s_barrier + lgkmcnt(0): no vmcnt(0) drain across phases.
//  - __launch_bounds__(256,1): 256-VGPR bucket (R7/R17: arg>=2 caps the
//    allocator at 128 and spills). LDS 66 KB caps residency at 2 blocks/CU
//    = 2 waves/SIMD regardless, which 256 VGPRs permits.
// Grid 512 x 256 (4 waves): q=w&1 batch-quad, h=w>>1 s-half;
// batches blk*8+q*4+{0..3}, s in [h*128,h*128+128), lane = f.
__global__ __launch_bounds__(256, 1) void fused_kernel(
    const float* __restrict__ x, const float4* __restrict__ Wl4,
    const float4* __restrict__ snip4, float4* __restrict__ out4) {
  __shared__ float4 Wbuf[2][2][1024];  // [half][parity][(s4*4+kq)*64+f] 64 KB
  __shared__ int idxs[8][64];          // [q*4+j][f]                     2 KB

  const int tid = threadIdx.x;
  const int lane = tid & 63;            // f
  const int w = tid >> 6;               // 0..3
  const int q = w & 1;                  // batch quad
  const int h = w >> 1;                 // s-half
  const int bbase = blockIdx.x * 8;
  const int b0 = bbase + q * 4;
  const size_t xrow = (size_t)Sn * Fn;
  const float* xb0 = x + (size_t)b0 * xrow + (size_t)(h * 128) * Fn + lane;
  const float4* wsrc0 = Wl4 + (size_t)(h * 128) * 256;  // this half's W rows

  float acc[4][16];
#pragma unroll
  for (int j = 0; j < 4; ++j)
#pragma unroll
    for (int k = 0; k < 16; ++k) acc[j][k] = 0.f;

  float x0[4][4], x1[4][4], x2[4][4], x3[4][4];  // rotating x buffers
  float4 wst[8];                                 // W reg-staging (1 chunk)

// issue W chunk c's global loads into wst (wave (q,h): rows c*4+2q, +2q+1
// = 512 float4 across the wave = 8 float4/lane). Wrap-masked.
#define LOADW(c)                                                             \
  {                                                                          \
    const float4* _s = wsrc0 + (size_t)(((c) & 31) * 4 + 2 * q) * 256 + lane;\
    _Pragma("unroll") for (int ii = 0; ii < 8; ++ii) wst[ii] = _s[ii * 64];  \
  }

// park wst into Wbuf[h][p] (compiler inserts counted vmcnt for wst here)
#define WRITEW(p)                                                            \
  {                                                                          \
    float4* _d = &Wbuf[h][p][(2 * q) * 256] + lane;                          \
    _Pragma("unroll") for (int ii = 0; ii < 8; ++ii) _d[ii * 64] = wst[ii];  \
  }

// load x chunk c (4 s x 4 b, 256 B coalesced wave-loads). Wrap-masked.
#define LOADX(c, xn)                                                         \
  {                                                                          \
    _Pragma("unroll") for (int s4 = 0; s4 < 4; ++s4)                         \
        _Pragma("unroll") for (int j = 0; j < 4; ++j)                        \
            xn[s4][j] =                                                      \
                xb0[(size_t)j * xrow + (size_t)(((c) & 31) * 4 + s4) * Fn];  \
  }

// compute chunk from Wbuf[h][p] and x buffer xn (NaN->0 applied at use)
#define COMPUTE(p, xn)                                                       \
  {                                                                          \
    _Pragma("unroll") for (int s4 = 0; s4 < 4; ++s4) {                       \
      float4 wq[4];                                                          \
      _Pragma("unroll") for (int kq = 0; kq < 4; ++kq)                       \
          wq[kq] = Wbuf[h][p][(s4 * 4 + kq) * 64 + lane];                    \
      float xv[4];                                                           \
      _Pragma("unroll") for (int j = 0; j < 4; ++j) {                        \
        float v = xn[s4][j];                                                 \
        xv[j] = (v == v) ? v : 0.f;                                          \
      }                                                                      \
      _Pragma("unroll") for (int j = 0; j < 4; ++j)                          \
          _Pragma("unroll") for (int kq = 0; kq < 4; ++kq) {                 \
        acc[j][4 * kq + 0] = fmaf(xv[j], wq[kq].x, acc[j][4 * kq + 0]);      \
        acc[j][4 * kq + 1] = fmaf(xv[j], wq[kq].y, acc[j][4 * kq + 1]);      \
        acc[j][4 * kq + 2] = fmaf(xv[j], wq[kq].z, acc[j][4 * kq + 2]);      \
        acc[j][4 * kq + 3] = fmaf(xv[j], wq[kq].w, acc[j][4 * kq + 3]);      \
      }                                                                      \
    }                                                                        \
  }

// phase c: issue W(c+1) (FIRST) and x(c+3); compute chunk c from Wbuf[p]
// (W(c) guaranteed by previous barrier); park W(c+1) into Wbuf[p^1]
// (safe: all reads of p^1 finished before the PREVIOUS barrier); barrier.
#define PHASE(c, xcur, xnext, p)                                             \
  {                                                                          \
    LOADW((c) + 1);                                                          \
    LOADX((c) + 3, xnext);                                                   \
    COMPUTE(p, xcur);                                                        \
    WRITEW((p) ^ 1);                                                         \
    BARRIER();                                                               \
  }

  // prologue: W(0) + x(0..2) issued; W(0) parked; barrier
  LOADW(0);
  LOADX(0, x0);
  LOADX(1, x1);
  LOADX(2, x2);
  WRITEW(0);
  BARRIER();

  // 32 chunks, 4-unrolled for static buffer rotation; parity = c&1
  for (int cc = 0; cc < 32; cc += 4) {
    PHASE(cc + 0, x0, x3, 0);
    PHASE(cc + 1, x1, x0, 1);
    PHASE(cc + 2, x2, x1, 0);
    PHASE(cc + 3, x3, x2, 1);
  }

  // full drain before aliasing Wbuf (wrap dummy loads still in flight)
  __syncthreads();

  // cross-half reduce in aliased Wbuf, then argmax
  float* red = reinterpret_cast<float*>(&Wbuf[0][0][0]);
  if (h == 1) {
#pragma unroll
    for (int j = 0; j < 4; ++j)
#pragma unroll
      for (int k = 0; k < 16; ++k)
        red[((q * 4 + j) * 16 + k) * 64 + lane] = acc[j][k];
  }
  __syncthreads();
  if (h == 0) {
#pragma unroll
    for (int j = 0; j < 4; ++j) {
#pragma unroll
      for (int k = 0; k < 16; ++k)
        acc[j][k] += red[((q * 4 + j) * 16 + k) * 64 + lane];
      float bv = acc[j][0];
      int bk = 0;
#pragma unroll
      for (int k = 1; k < 16; ++k)
        if (acc[j][k] > bv) { bv = acc[j][k]; bk = k; }  // first max wins
      idxs[q * 4 + j][lane] = bk;
    }
  }
  __syncthreads();

  // fused gather: 8 b * 64 f = 512 rows of 1 KB, coalesced float4
#pragma unroll 4
  for (int it = 0; it < 128; ++it) {
    int r = (it << 2) | w;
    int bi = r >> 6, f = r & 63;
    int kk = idxs[bi][f];
    float4 v = snip4[(size_t)((f * Kn + kk) << 6) + lane];
    out4[((size_t)(bbase + bi) * Fn + f) * 64 + lane] = v;
  }
#undef LOADW
#undef WRITEW
#undef LOADX
#undef COMPUTE
#undef PHASE
}

// Fallback (ws too small): R5's verified fused kernel, direct W reads.
__global__ __launch_bounds__(256, 2) void fused_fallback(
    const float* __restrict__ x, const float* __restrict__ Wsrc,
    const float4* __restrict__ snip4, float4* __restrict__ out4) {
  __shared__ int idxs[8][64];
  const int tid = threadIdx.x;
  const int lane = tid & 63;
  const int w = tid >> 6;
  const int bbase = blockIdx.x * 8;
  const int b0 = bbase + w * 2;
  const size_t xrow = (size_t)Sn * Fn;

  float acc0[16], acc1[16];
#pragma unroll
  for (int k = 0; k < 16; ++k) { acc0[k] = 0.f; acc1[k] = 0.f; }
  const float* pc0 = x + (size_t)b0 * xrow + lane;
  const float* pc1 = pc0 + xrow;
  float xc0[8], xc1[8], xn0[8], xn1[8];
#pragma unroll
  for (int j = 0; j < 8; ++j) { xn0[j] = pc0[j * 64]; xn1[j] = pc1[j * 64]; }
  for (int c = 0; c < 32; ++c) {
#pragma unroll
    for (int j = 0; j < 8; ++j) {
      float v0 = xn0[j], v1 = xn1[j];
      xc0[j] = (v0 == v0) ? v0 : 0.f;
      xc1[j] = (v1 == v1) ? v1 : 0.f;
    }
    if (c < 31) {
      pc0 += 512; pc1 += 512;
#pragma unroll
      for (int j = 0; j < 8; ++j) { xn0[j] = pc0[j * 64]; xn1[j] = pc1[j * 64]; }
    }
#pragma unroll
    for (int s8 = 0; s8 < 8; ++s8) {
      const int s = c * 8 + s8;
      float wv[16];
      const float4* wq = reinterpret_cast<const float4*>(Wsrc) + ((size_t)(lane * Sn + s) << 2);
#pragma unroll
      for (int jj = 0; jj < 4; ++jj) {
        float4 qv = wq[jj];
        wv[4 * jj + 0] = qv.x; wv[4 * jj + 1] = qv.y; wv[4 * jj + 2] = qv.z; wv[4 * jj + 3] = qv.w;
      }
#pragma unroll
      for (int k = 0; k < 16; ++k) {
        acc0[k] = fmaf(xc0[s8], wv[k], acc0[k]);
        acc1[k] = fmaf(xc1[s8], wv[k], acc1[k]);
      }
    }
  }
  {
    float bv0 = acc0[0], bv1 = acc1[0];
    int bk0 = 0, bk1 = 0;
#pragma unroll
    for (int k = 1; k < 16; ++k) {
      if (acc0[k] > bv0) { bv0 = acc0[k]; bk0 = k; }
      if (acc1[k] > bv1) { bv1 = acc1[k]; bk1 = k; }
    }
    idxs[w * 2 + 0][lane] = bk0;
    idxs[w * 2 + 1][lane] = bk1;
  }
  __syncthreads();
#pragma unroll 4
  for (int it = 0; it < 128; ++it) {
    int r = (it << 2) | w;
    int bi = r >> 6, f = r & 63;
    int kk = idxs[bi][f];
    float4 v = snip4[(size_t)((f * Kn + kk) << 6) + lane];
    out4[((size_t)(bbase + bi) * Fn + f) * 64 + lane] = v;
  }
}

extern "C" void kernel_launch(void* const* d_in, const int* in_sizes, int n_in,
                              void* d_out, int out_size, void* d_ws, size_t ws_size,
                              hipStream_t stream) {
  const float* x = (const float*)d_in[0];
  const float* W = (const float*)d_in[1];
  const float* snip = (const float*)d_in[2];
  float4* out4 = (float4*)d_out;
  const float4* snip4 = (const float4*)snip;

  const size_t wl_bytes = (size_t)Sn * Fn * Kn * sizeof(float);   // 1 MB
  if (ws_size >= wl_bytes) {
    float* Wl = (float*)d_ws;
    transpose_w_kernel<<<(Sn * Fn * Kn) / 256, 256, 0, stream>>>(W, Wl);
    fused_kernel<<<Bn / 8, 256, 0, stream>>>(x, (const float4*)Wl, snip4, out4);
  } else {
    fused_fallback<<<Bn / 8, 256, 0, stream>>>(x, W, snip4, out4);
  }
}